// Round 1
// baseline (24.354 us; speedup 1.0000x reference)
//
#include <hip/hip_runtime.h>

#define EPSV 1e-4f

// One cyclic-Jacobi rotation for the symmetric 3x3, pair (p,q), other index r.
// app=A(p,p), aqq=A(q,q), apq=A(p,q), arp=A(r,p), arq=A(r,q).
// (vap,vaq),(vbp,vbq),(vcp,vcq) are rows 0..2 of V restricted to columns p,q.
__device__ __forceinline__ void jrot(float& app, float& aqq, float& apq,
                                     float& arp, float& arq,
                                     float& vap, float& vaq,
                                     float& vbp, float& vbq,
                                     float& vcp, float& vcq) {
  const float apq0 = apq;
  float tau = (aqq - app) / (2.0f * apq0);               // may be inf/nan if apq0==0
  float t = copysignf(1.0f / (fabsf(tau) + sqrtf(fmaf(tau, tau, 1.0f))), tau);
  if (apq0 == 0.0f) t = 0.0f;                            // covers the nan case too
  const float c = rsqrtf(fmaf(t, t, 1.0f));
  const float s = t * c;
  const float d = t * apq0;
  app -= d; aqq += d; apq = 0.0f;
  const float rp = arp, rq = arq;
  arp = c * rp - s * rq;
  arq = s * rp + c * rq;
  float x, y;
  x = vap; y = vaq; vap = c * x - s * y; vaq = s * x + c * y;
  x = vbp; y = vbq; vbp = c * x - s * y; vbq = s * x + c * y;
  x = vcp; y = vcq; vcp = c * x - s * y; vcq = s * x + c * y;
}

__global__ __launch_bounds__(256) void spd_decoder_kernel(
    const float* __restrict__ vech, const float* __restrict__ W1,
    const float* __restrict__ W2, const float* __restrict__ W3,
    float* __restrict__ out, int B) {
  __shared__ float Tsh[21];                 // W2@W1 (7x3)
  __shared__ float Msh[27];                 // W3@W2@W1 (9x3)
  __shared__ __align__(16) float buf[4][32 * 81];  // per-wave staging, 41472 B

  const int tid = threadIdx.x;

  // ---- per-block precompute of M = W3@W2@W1 (cheap, redundant per block) ----
  if (tid < 21) {
    const int r = tid / 3, c = tid % 3;
    float acc = 0.f;
#pragma unroll
    for (int j = 0; j < 5; ++j) acc += W2[r * 5 + j] * W1[j * 3 + c];
    Tsh[tid] = acc;
  }
  __syncthreads();
  if (tid < 27) {
    const int r = tid / 3, c = tid % 3;
    float acc = 0.f;
#pragma unroll
    for (int j = 0; j < 7; ++j) acc += W3[r * 7 + j] * Tsh[j * 3 + c];
    Msh[tid] = acc;
  }
  __syncthreads();

  float M[27];
#pragma unroll
  for (int i = 0; i < 27; ++i) M[i] = Msh[i];

  // ---- load vech, build symmetric 3x3 ----
  const int e = blockIdx.x * 256 + tid;     // B is a multiple of 256
  const float2* vp = reinterpret_cast<const float2*>(vech + (size_t)e * 6);
  const float2 p0 = vp[0], p1 = vp[1], p2 = vp[2];
  float a00 = p0.x, a01 = p0.y, a02 = p1.x, a11 = p1.y, a12 = p2.x, a22 = p2.y;

  // ---- 3x3 Jacobi eigendecomposition, V accumulated ----
  float v00 = 1.f, v01 = 0.f, v02 = 0.f;
  float v10 = 0.f, v11 = 1.f, v12 = 0.f;
  float v20 = 0.f, v21 = 0.f, v22 = 1.f;
#pragma unroll
  for (int sweep = 0; sweep < 5; ++sweep) {
    jrot(a00, a11, a01, a02, a12, v00, v01, v10, v11, v20, v21);  // (0,1), r=2
    jrot(a00, a22, a02, a01, a12, v00, v02, v10, v12, v20, v22);  // (0,2), r=1
    jrot(a11, a22, a12, a01, a02, v01, v02, v11, v12, v21, v22);  // (1,2), r=0
  }

  const float e0 = expf(a00) - EPSV;
  const float e1 = expf(a11) - EPSV;
  const float e2 = expf(a22) - EPSV;

  // ---- out = sum_k e_k * (M v_k)(M v_k)^T  + eps*I, symmetric upper (45) ----
  float o[45];
#pragma unroll
  for (int i = 0; i < 45; ++i) o[i] = 0.f;

#define ACCUM_COL(vk0, vk1, vk2, ek)                                   \
  {                                                                    \
    float g[9];                                                        \
    _Pragma("unroll") for (int i = 0; i < 9; ++i)                      \
        g[i] = fmaf(M[i * 3 + 0], (vk0),                               \
                    fmaf(M[i * 3 + 1], (vk1), M[i * 3 + 2] * (vk2)));  \
    int idx = 0;                                                       \
    _Pragma("unroll") for (int i = 0; i < 9; ++i) {                    \
      const float sgi = (ek)*g[i];                                     \
      _Pragma("unroll") for (int j = i; j < 9; ++j) {                  \
        o[idx] = fmaf(sgi, g[j], o[idx]);                              \
        ++idx;                                                         \
      }                                                                \
    }                                                                  \
  }

  ACCUM_COL(v00, v10, v20, e0);
  ACCUM_COL(v01, v11, v21, e1);
  ACCUM_COL(v02, v12, v22, e2);
#undef ACCUM_COL

  {  // diagonal += eps
    int idx = 0;
#pragma unroll
    for (int i = 0; i < 9; ++i) {
      o[idx] += EPSV;
      idx += 9 - i;
    }
  }

  // ---- staged, coalesced store: per wave, two half-phases of 32 elements ----
  const int w = tid >> 6, l = tid & 63;
  float* wbuf = &buf[w][0];
  const size_t base = (size_t)(blockIdx.x * 256 + w * 64) * 81;

#pragma unroll
  for (int h = 0; h < 2; ++h) {
    __syncthreads();  // protect LDS buffer reuse across phases
    if ((l >> 5) == h) {
      const int ll = l & 31;
#pragma unroll
      for (int i = 0; i < 9; ++i) {
#pragma unroll
        for (int j = 0; j < 9; ++j) {
          const int ii = i < j ? i : j;
          const int jj = i < j ? j : i;
          const int a = ii * 9 - ii * (ii - 1) / 2 + (jj - ii);
          wbuf[ll * 81 + i * 9 + j] = o[a];  // stride 81 (mod 32 = 17): conflict-free
        }
      }
    }
    __syncthreads();
    // store 2592 contiguous floats (32 elements * 81), 16B-aligned region
    const size_t sb = base + (size_t)h * 2592;
    const float4* rbuf = reinterpret_cast<const float4*>(wbuf);
    float4* outv = reinterpret_cast<float4*>(out + sb);
#pragma unroll
    for (int it = 0; it < 10; ++it) outv[it * 64 + l] = rbuf[it * 64 + l];
    if (l < 32) out[sb + 2560 + l] = wbuf[2560 + l];  // tail 32 floats
  }
}

extern "C" void kernel_launch(void* const* d_in, const int* in_sizes, int n_in,
                              void* d_out, int out_size, void* d_ws, size_t ws_size,
                              hipStream_t stream) {
  const float* vech = (const float*)d_in[0];
  const float* W1 = (const float*)d_in[1];
  const float* W2 = (const float*)d_in[2];
  const float* W3 = (const float*)d_in[3];
  float* out = (float*)d_out;
  const int B = in_sizes[0] / 6;  // 262144
  dim3 grid(B / 256), block(256);
  hipLaunchKernelGGL(spd_decoder_kernel, grid, block, 0, stream,
                     vech, W1, W2, W3, out, B);
}